// Round 1
// baseline (3701.653 us; speedup 1.0000x reference)
//
#include <hip/hip_runtime.h>
#include <hip/hip_bf16.h>

#define LAYERS 6
#define NN 9
#define NHEAD 8
#define HD 16

// ---------------------------------------------------------------------------
// K0: precompute per-layer/head  M_h = 0.25 * Aq_h @ Ak_h^T  (9x9)
//                                N_h = Av_h @ Wo_h           (9x9)
// MN layout: [l][h][2][81]
// ---------------------------------------------------------------------------
__global__ void k_precompute(const float* __restrict__ Wq, const float* __restrict__ Wk,
                             const float* __restrict__ Wv, const float* __restrict__ Wo,
                             float* __restrict__ MN)
{
    const int l  = blockIdx.x;   // 0..5
    const int ht = blockIdx.y;   // 0..7
    const int t  = threadIdx.x;  // 0..191
    if (t < 81) {
        const int a = t / 9, b = t % 9;
        float s = 0.f;
        for (int d = 0; d < HD; ++d)
            s += Wq[(l * NN + a) * 128 + ht * HD + d] * Wk[(l * NN + b) * 128 + ht * HD + d];
        MN[((size_t)(l * NHEAD + ht) * 2 + 0) * 81 + t] = s * 0.25f;
    } else if (t < 162) {
        const int u = t - 81;
        const int a = u / 9, b = u % 9;
        float s = 0.f;
        for (int d = 0; d < HD; ++d)
            s += Wv[(l * NN + a) * 128 + ht * HD + d] * Wo[((size_t)l * 128 + ht * HD + d) * NN + b];
        MN[((size_t)(l * NHEAD + ht) * 2 + 1) * 81 + u] = s;
    }
}

// ---------------------------------------------------------------------------
// K1: transformer, one thread per batch element, everything in registers.
// Writes adj (81 floats) + z = adj@x (9 floats) to scratch.
// layout_soa==1: scratch[i*Bn + b]  (coalesced);  ==0: scratch[b*1440 + i]
// ---------------------------------------------------------------------------
__global__ void __launch_bounds__(256) k_transformer(
    const float* __restrict__ xg, const float* __restrict__ MN,
    const float* __restrict__ bo,
    const float* __restrict__ ln1g, const float* __restrict__ ln1b,
    const float* __restrict__ ln2g, const float* __restrict__ ln2b,
    const float* __restrict__ Wf1, const float* __restrict__ bf1,
    const float* __restrict__ Wf2, const float* __restrict__ bf2,
    float* __restrict__ scratch, int Bn, int layout_soa)
{
    const int b = blockIdx.x * 256 + threadIdx.x;
    if (b >= Bn) return;
    const float* __restrict__ xp = xg + (size_t)b * NN;

    float h[81];
#pragma unroll
    for (int i = 0; i < 9; ++i) {
        const float xv = xp[i];
#pragma unroll
        for (int j = 0; j < 9; ++j) h[i * 9 + j] = (i == j) ? xv : 0.f;
    }

    for (int l = 0; l < LAYERS; ++l) {
        float acc[81];
#pragma unroll
        for (int i = 0; i < 81; ++i) acc[i] = 0.f;

        for (int ht = 0; ht < NHEAD; ++ht) {
            const float* __restrict__ Mw = MN + ((size_t)(l * NHEAD + ht) * 2) * 81;
            const float* __restrict__ Nw = Mw + 81;

            // T = h @ M
            float T[81];
#pragma unroll
            for (int a = 0; a < 9; ++a)
#pragma unroll
                for (int k = 0; k < 9; ++k) {
                    float s = 0.f;
#pragma unroll
                    for (int m = 0; m < 9; ++m) s += h[a * 9 + m] * Mw[m * 9 + k];
                    T[a * 9 + k] = s;
                }

            // per row: S = T@h^T, softmax, Q = P@h  (Q overwrites T in place)
#pragma unroll
            for (int a = 0; a < 9; ++a) {
                float sr[9];
#pragma unroll
                for (int j = 0; j < 9; ++j) {
                    float s = 0.f;
#pragma unroll
                    for (int k = 0; k < 9; ++k) s += T[a * 9 + k] * h[j * 9 + k];
                    sr[j] = s;
                }
                float mx = sr[0];
#pragma unroll
                for (int j = 1; j < 9; ++j) mx = fmaxf(mx, sr[j]);
                float sum = 0.f;
#pragma unroll
                for (int j = 0; j < 9; ++j) { sr[j] = __expf(sr[j] - mx); sum += sr[j]; }
                const float inv = __builtin_amdgcn_rcpf(sum);
#pragma unroll
                for (int j = 0; j < 9; ++j) sr[j] *= inv;
                float qr[9];
#pragma unroll
                for (int c = 0; c < 9; ++c) {
                    float s = 0.f;
#pragma unroll
                    for (int k = 0; k < 9; ++k) s += sr[k] * h[k * 9 + c];
                    qr[c] = s;
                }
#pragma unroll
                for (int c = 0; c < 9; ++c) T[a * 9 + c] = qr[c];
            }

            // acc += Q @ N
#pragma unroll
            for (int a = 0; a < 9; ++a)
#pragma unroll
                for (int c = 0; c < 9; ++c) {
                    const float qv = T[a * 9 + c];
#pragma unroll
                    for (int j = 0; j < 9; ++j) acc[a * 9 + j] += qv * Nw[c * 9 + j];
                }
        }

        // h = LN1(h + acc + bo)
#pragma unroll
        for (int a = 0; a < 9; ++a) {
            float r[9]; float mean = 0.f;
#pragma unroll
            for (int j = 0; j < 9; ++j) { r[j] = h[a * 9 + j] + acc[a * 9 + j] + bo[l * 9 + j]; mean += r[j]; }
            mean *= (1.f / 9.f);
            float var = 0.f;
#pragma unroll
            for (int j = 0; j < 9; ++j) { const float d = r[j] - mean; var += d * d; }
            var *= (1.f / 9.f);
            const float rs = __builtin_amdgcn_rsqf(var + 1e-5f);
#pragma unroll
            for (int j = 0; j < 9; ++j) h[a * 9 + j] = (r[j] - mean) * rs * ln1g[l * 9 + j] + ln1b[l * 9 + j];
        }

        // FF: acc = relu(h@Wf1 + bf1) @ Wf2   (streamed over f)
#pragma unroll
        for (int i = 0; i < 81; ++i) acc[i] = 0.f;
        for (int f = 0; f < 40; ++f) {
            const float bb = bf1[l * 40 + f];
            float w2[9];
#pragma unroll
            for (int j = 0; j < 9; ++j) w2[j] = Wf2[((size_t)l * 40 + f) * 9 + j];
#pragma unroll
            for (int a = 0; a < 9; ++a) {
                float s = bb;
#pragma unroll
                for (int m = 0; m < 9; ++m) s += h[a * 9 + m] * Wf1[((size_t)l * 9 + m) * 40 + f];
                s = fmaxf(s, 0.f);
#pragma unroll
                for (int j = 0; j < 9; ++j) acc[a * 9 + j] += s * w2[j];
            }
        }

        // h = LN2(h + acc + bf2)
#pragma unroll
        for (int a = 0; a < 9; ++a) {
            float r[9]; float mean = 0.f;
#pragma unroll
            for (int j = 0; j < 9; ++j) { r[j] = h[a * 9 + j] + acc[a * 9 + j] + bf2[l * 9 + j]; mean += r[j]; }
            mean *= (1.f / 9.f);
            float var = 0.f;
#pragma unroll
            for (int j = 0; j < 9; ++j) { const float d = r[j] - mean; var += d * d; }
            var *= (1.f / 9.f);
            const float rs = __builtin_amdgcn_rsqf(var + 1e-5f);
#pragma unroll
            for (int j = 0; j < 9; ++j) h[a * 9 + j] = (r[j] - mean) * rs * ln2g[l * 9 + j] + ln2b[l * 9 + j];
        }
    }

    // write adj (=h) and z = adj @ x
    if (layout_soa) {
#pragma unroll
        for (int i = 0; i < 81; ++i) scratch[(size_t)i * Bn + b] = h[i];
#pragma unroll
        for (int a = 0; a < 9; ++a) {
            float s = 0.f;
#pragma unroll
            for (int k = 0; k < 9; ++k) s += h[a * 9 + k] * xp[k];
            scratch[(size_t)(81 + a) * Bn + b] = s;
        }
    } else {
        float* op = scratch + (size_t)b * 1440;
#pragma unroll
        for (int i = 0; i < 81; ++i) op[i] = h[i];
#pragma unroll
        for (int a = 0; a < 9; ++a) {
            float s = 0.f;
#pragma unroll
            for (int k = 0; k < 9; ++k) s += h[a * 9 + k] * xp[k];
            op[81 + a] = s;
        }
    }
}

// ---------------------------------------------------------------------------
// K2: GCN, one 64-lane wave per batch element. Stages:
//   m2 = adj @ LR(z ⊗ w1);  y1 = LR(m2 @ Wg1);  m3 = adj @ y1;
//   y2 = LR(m3 @ Wg2) -> out
// ---------------------------------------------------------------------------
__global__ void __launch_bounds__(64) k_gcn(
    const float* __restrict__ scratch, const float* __restrict__ w1,
    const float* __restrict__ Wg1, const float* __restrict__ Wg2,
    float* __restrict__ out, int Bn, int layout_soa)
{
    __shared__ float adjs[81];
    __shared__ float zs[9];
    __shared__ float m2s[9 * 40];
    __shared__ float y1s[9 * 80];
    __shared__ float m3s[9 * 80];

    const int b = blockIdx.x;
    const int l = threadIdx.x;

    if (layout_soa) {
        adjs[l] = scratch[(size_t)l * Bn + b];
        if (l < 17) adjs[64 + l] = scratch[(size_t)(64 + l) * Bn + b];
        if (l < 9)  zs[l] = scratch[(size_t)(81 + l) * Bn + b];
    } else {
        const float* src = scratch + (size_t)b * 1440;
        adjs[l] = src[l];
        if (l < 17) adjs[64 + l] = src[64 + l];
        if (l < 9)  zs[l] = src[81 + l];
    }
    __syncthreads();

    // stage 1: m2[a][c] = sum_k adj[a][k] * LR(z[k]*w1[c])
    for (int o = l; o < 360; o += 64) {
        const int c = o / 9, a = o - c * 9;
        const float wc = w1[c];
        float s = 0.f;
#pragma unroll
        for (int k = 0; k < 9; ++k) {
            float nv = zs[k] * wc;
            nv = nv > 0.f ? nv : 0.2f * nv;
            s += adjs[a * 9 + k] * nv;
        }
        m2s[a * 40 + c] = s;
    }
    __syncthreads();

    // stage 2: y1[a][j] = LR( sum_f m2[a][f] * Wg1[f][j] )
    for (int j = l; j < 80; j += 64) {
        float acc[9];
#pragma unroll
        for (int a = 0; a < 9; ++a) acc[a] = 0.f;
        for (int f = 0; f < 40; f += 4) {
            const float w0 = Wg1[(size_t)f * 80 + j];
            const float wA = Wg1[(size_t)(f + 1) * 80 + j];
            const float wB = Wg1[(size_t)(f + 2) * 80 + j];
            const float wC = Wg1[(size_t)(f + 3) * 80 + j];
#pragma unroll
            for (int a = 0; a < 9; ++a) {
                const float4 v = *reinterpret_cast<const float4*>(&m2s[a * 40 + f]);
                acc[a] += v.x * w0 + v.y * wA + v.z * wB + v.w * wC;
            }
        }
#pragma unroll
        for (int a = 0; a < 9; ++a) {
            const float t = acc[a];
            y1s[a * 80 + j] = t > 0.f ? t : 0.2f * t;
        }
    }
    __syncthreads();

    // hoist adj into registers for stage 3
    float ar[81];
#pragma unroll
    for (int i = 0; i < 81; ++i) ar[i] = adjs[i];

    // stage 3: m3[a][j] = sum_k adj[a][k] * y1[k][j]
    for (int j = l; j < 80; j += 64) {
        float acc[9];
#pragma unroll
        for (int a = 0; a < 9; ++a) acc[a] = 0.f;
#pragma unroll
        for (int k = 0; k < 9; ++k) {
            const float yv = y1s[k * 80 + j];
#pragma unroll
            for (int a = 0; a < 9; ++a) acc[a] += ar[a * 9 + k] * yv;
        }
#pragma unroll
        for (int a = 0; a < 9; ++a) m3s[a * 80 + j] = acc[a];
    }
    __syncthreads();

    // stage 4: y2[a][c] = LR( sum_f m3[a][f] * Wg2[f][c] ) -> out
    float a0[9], a1[9], a2[9];
#pragma unroll
    for (int a = 0; a < 9; ++a) { a0[a] = 0.f; a1[a] = 0.f; a2[a] = 0.f; }
    const bool h2 = (l < 32);
    const int c0 = l, c1 = l + 64, c2 = l + 128;
    for (int f = 0; f < 80; f += 4) {
        float wA[4], wB[4], wC[4];
#pragma unroll
        for (int q = 0; q < 4; ++q) {
            wA[q] = Wg2[(size_t)(f + q) * 160 + c0];
            wB[q] = Wg2[(size_t)(f + q) * 160 + c1];
            wC[q] = h2 ? Wg2[(size_t)(f + q) * 160 + c2] : 0.f;
        }
#pragma unroll
        for (int a = 0; a < 9; ++a) {
            const float4 v = *reinterpret_cast<const float4*>(&m3s[a * 80 + f]);
            a0[a] += v.x * wA[0] + v.y * wA[1] + v.z * wA[2] + v.w * wA[3];
            a1[a] += v.x * wB[0] + v.y * wB[1] + v.z * wB[2] + v.w * wB[3];
            a2[a] += v.x * wC[0] + v.y * wC[1] + v.z * wC[2] + v.w * wC[3];
        }
    }
    float* op = out + (size_t)b * 1440;
#pragma unroll
    for (int a = 0; a < 9; ++a) {
        const float t0 = a0[a]; op[a * 160 + c0] = t0 > 0.f ? t0 : 0.2f * t0;
        const float t1 = a1[a]; op[a * 160 + c1] = t1 > 0.f ? t1 : 0.2f * t1;
        if (h2) { const float t2 = a2[a]; op[a * 160 + c2] = t2 > 0.f ? t2 : 0.2f * t2; }
    }
}

// ---------------------------------------------------------------------------
extern "C" void kernel_launch(void* const* d_in, const int* in_sizes, int n_in,
                              void* d_out, int out_size, void* d_ws, size_t ws_size,
                              hipStream_t stream)
{
    const float* x    = (const float*)d_in[0];
    const float* Wq   = (const float*)d_in[2];
    const float* Wk   = (const float*)d_in[4];
    const float* Wv   = (const float*)d_in[6];
    const float* Wo   = (const float*)d_in[8];
    const float* bo   = (const float*)d_in[9];
    const float* ln1g = (const float*)d_in[10];
    const float* ln1b = (const float*)d_in[11];
    const float* ln2g = (const float*)d_in[12];
    const float* ln2b = (const float*)d_in[13];
    const float* Wf1  = (const float*)d_in[14];
    const float* bf1  = (const float*)d_in[15];
    const float* Wf2  = (const float*)d_in[16];
    const float* bf2  = (const float*)d_in[17];
    const float* wg1c = (const float*)d_in[18];  // W_gcn1 [1,40]
    const float* Wg1  = (const float*)d_in[19];  // [40,80]
    const float* Wg2  = (const float*)d_in[20];  // [80,160]

    const int Bn = in_sizes[0] / NN;

    float* MN = (float*)d_ws;                    // 7776 floats
    const size_t mn_floats = (size_t)LAYERS * NHEAD * 2 * 81;
    const size_t need = (mn_floats + (size_t)Bn * 90) * sizeof(float);
    const int use_ws_scratch = (ws_size >= need) ? 1 : 0;
    float* adjz = use_ws_scratch ? (MN + mn_floats) : (float*)d_out;

    k_precompute<<<dim3(LAYERS, NHEAD), 192, 0, stream>>>(Wq, Wk, Wv, Wo, MN);

    const int nblk = (Bn + 255) / 256;
    k_transformer<<<nblk, 256, 0, stream>>>(x, MN, bo, ln1g, ln1b, ln2g, ln2b,
                                            Wf1, bf1, Wf2, bf2, adjz, Bn, use_ws_scratch);

    k_gcn<<<Bn, 64, 0, stream>>>(adjz, wg1c, Wg1, Wg2, (float*)d_out, Bn, use_ws_scratch);
}